// Round 4
// baseline (225.143 us; speedup 1.0000x reference)
//
#include <hip/hip_runtime.h>
#include <hip/hip_bf16.h>

typedef unsigned short ushort_t;
typedef __attribute__((ext_vector_type(4))) float f32x4;
typedef __attribute__((ext_vector_type(8))) short bf16x8;
typedef __attribute__((ext_vector_type(8))) unsigned short u16x8;

#define M_DIM 2048
#define N_DIM 4096
#define K_DIM 4096
#define BM 256
#define BN 128
#define BK 64
#define NT (K_DIM / BK)   // 64 K-tiles

#define MFMA16(a, b, c) __builtin_amdgcn_mfma_f32_16x16x32_bf16((a), (b), (c), 0, 0, 0)

// ---------- helpers ----------
__device__ __forceinline__ unsigned short f2bf(float f) {
  unsigned int u = __float_as_uint(f);
  u += 0x7FFFu + ((u >> 16) & 1u);   // round-to-nearest-even
  return (unsigned short)(u >> 16);
}

__device__ __forceinline__ void async16(void* l, const void* g) {
  __builtin_amdgcn_global_load_lds(
      (const __attribute__((address_space(1))) void*)g,
      (__attribute__((address_space(3))) void*)l,
      16, 0, 0);
}

// ---------- kernel 1: fused [x fp32->bf16] + [W build with on-the-fly T01] ----------
// blocks [0,2048): convert x; blocks [2048,6144): Wt[out][in] bf16
__global__ void k_prep(const float* __restrict__ x, ushort_t* __restrict__ o,
                       const float* __restrict__ c0, const float* __restrict__ c1,
                       const float* __restrict__ c2, ushort_t* __restrict__ wt) {
  const int bid = blockIdx.x;
  const int tid = threadIdx.x;
  if (bid < 2048) {
    const int n4 = (M_DIM * K_DIM) / 4;
    for (int i = bid * 256 + tid; i < n4; i += 2048 * 256) {
      float4 v = ((const float4*)x)[i];
      ushort4 r;
      r.x = f2bf(v.x); r.y = f2bf(v.y); r.z = f2bf(v.z); r.w = f2bf(v.w);
      ((ushort4*)o)[i] = r;
    }
  } else {
    const int t = (bid - 2048) * 256 + tid;   // 1M threads, 16 outputs each
    const int i2 = t & 15;
    const int i1 = (t >> 4) & 15;
    const int out = t >> 8;                    // 0..4095
    const int o3 = out & 15;
    const int o2 = (out >> 4) & 15;
    const int o1 = out >> 8;
    // t01r[r] = sum_q c0[i1,o1,q] * c1[q,i2,o2,r]
    float t01r[16];
    #pragma unroll
    for (int r = 0; r < 16; ++r) t01r[r] = 0.f;
    const float* c0p = c0 + (i1 * 16 + o1) * 16;
    const float* c1p = c1 + i2 * 256 + o2 * 16;
    #pragma unroll
    for (int q = 0; q < 16; ++q) {
      const float a = c0p[q];
      #pragma unroll
      for (int r = 0; r < 16; ++r) t01r[r] += a * c1p[q * 4096 + r];
    }
    // s[i3] = sum_r t01r[r] * c2[r,i3,o3]
    u16x8 lo, hi;
    #pragma unroll
    for (int i3 = 0; i3 < 16; ++i3) {
      const float* c2p = c2 + i3 * 16 + o3;
      float s = 0.f;
      #pragma unroll
      for (int rr = 0; rr < 16; ++rr) s += t01r[rr] * c2p[rr * 256];
      ushort_t v = f2bf(s);
      if (i3 < 8) lo[i3] = v; else hi[i3 - 8] = v;
    }
    u16x8* dst = (u16x8*)(wt + ((size_t)out << 12) + (i1 << 8) + (i2 << 4));
    dst[0] = lo;
    dst[1] = hi;
  }
}

// ---------- kernel 2: GEMM C[M][N] = A[M][K] * Wt[N][K]^T + bias ----------
// BM=256 BN=128 BK=64, 512 thr (8 waves 4Mx2N, 64x64 each), triple-buffered LDS,
// 2 phases/K-tile (16 MFMA each), 2 barriers/phase, counted vmcnt(6) once per
// tile, both-sides XOR swizzle (verified 0 conflicts), setprio around MFMA.
__global__ __launch_bounds__(512, 2) void k_gemm(
    const ushort_t* __restrict__ A,
    const ushort_t* __restrict__ Bt,
    const float* __restrict__ bias,
    float* __restrict__ C)
{
  __shared__ ushort_t lA[3][BM * BK];   // 3 x 32KB
  __shared__ ushort_t lB[3][BN * BK];   // 3 x 16KB  (total 144KB)

  const int tid  = threadIdx.x;
  const int lane = tid & 63;
  const int wid  = tid >> 6;     // 0..7
  const int wm   = wid >> 1;     // 0..3  (M quadrant, 64 rows)
  const int wn   = wid & 1;      // 0..1  (N half, 64 cols)
  const int fr   = lane & 15;
  const int fg   = lane >> 4;    // 0..3

  // XCD swizzle: 256 wgs; bm = bid&7 -> each XCD owns one A-panel (2MB, L2-fit)
  const int bid = blockIdx.x;
  const int bm  = bid & 7;       // 0..7
  const int bn  = bid >> 3;      // 0..31

  // ---- staging (linear LDS dest + inverse-swizzled global source) ----
  const int srow = tid >> 3;                               // 0..63
  const int scol = ((tid & 7) ^ (srow & 7)) << 3;          // swizzled source col (elems)
  const ushort_t* aSt = A  + (size_t)(bm * BM + srow) * K_DIM + scol;
  const ushort_t* bSt = Bt + (size_t)(bn * BN + srow) * K_DIM + scol;
  const int dE = tid * 8;                                  // linear dest (elems)

#define STAGE_A(kt, s, r_) async16(&lA[s][(r_) * 4096 + dE], \
                                   aSt + (size_t)(kt) * BK + (size_t)(r_) * 64 * K_DIM)
#define STAGE_B(kt, s, r_) async16(&lB[s][(r_) * 4096 + dE], \
                                   bSt + (size_t)(kt) * BK + (size_t)(r_) * 64 * K_DIM)

  // ---- fragment read addressing (swizzle applied on read) ----
  const int arowb = wm * 64 + fr;                // + m*16
  const int browb = wn * 64 + fr;                // + n*16
  const int c0 = ( fg      ^ (fr & 7)) << 3;     // kk=0 col (elems)
  const int c1 = ((fg + 4) ^ (fr & 7)) << 3;     // kk=1

  f32x4 acc[4][4];
  #pragma unroll
  for (int m = 0; m < 4; ++m)
    #pragma unroll
    for (int n = 0; n < 4; ++n)
      acc[m][n] = (f32x4){0.f, 0.f, 0.f, 0.f};

  // prologue: stage tiles 0,1 (6 chunks each)
  #pragma unroll
  for (int r_ = 0; r_ < 4; ++r_) STAGE_A(0, 0, r_);
  #pragma unroll
  for (int r_ = 0; r_ < 2; ++r_) STAGE_B(0, 0, r_);
  #pragma unroll
  for (int r_ = 0; r_ < 4; ++r_) STAGE_A(1, 1, r_);
  #pragma unroll
  for (int r_ = 0; r_ < 2; ++r_) STAGE_B(1, 1, r_);

  asm volatile("s_waitcnt vmcnt(6)" ::: "memory");   // tile 0 resident (per-wave)
  __builtin_amdgcn_s_barrier();                      // ... for ALL waves

  int sc = 0, ss = 2;
  for (int t = 0; t < NT; ++t) {
    const bool pre = (t + 2 < NT);
    const ushort_t* pA = &lA[sc][0];
    const ushort_t* pB = &lB[sc][0];

    // ================= phase 0: kk=0 (16 MFMA) =================
    {
      bf16x8 af[4], bf[4];
      #pragma unroll
      for (int m = 0; m < 4; ++m) af[m] = *(const bf16x8*)(pA + (arowb + m * 16) * 64 + c0);
      #pragma unroll
      for (int n = 0; n < 4; ++n) bf[n] = *(const bf16x8*)(pB + (browb + n * 16) * 64 + c0);
      if (pre) { STAGE_A(t + 2, ss, 0); STAGE_A(t + 2, ss, 1); STAGE_A(t + 2, ss, 2); }
      __builtin_amdgcn_s_barrier();
      __builtin_amdgcn_s_setprio(1);
      #pragma unroll
      for (int m = 0; m < 4; ++m)
        #pragma unroll
        for (int n = 0; n < 4; ++n)
          acc[m][n] = MFMA16(af[m], bf[n], acc[m][n]);
      __builtin_amdgcn_s_setprio(0);
      __builtin_amdgcn_s_barrier();
    }

    // ================= phase 1: kk=1 (16 MFMA) =================
    {
      bf16x8 af[4], bf[4];
      #pragma unroll
      for (int m = 0; m < 4; ++m) af[m] = *(const bf16x8*)(pA + (arowb + m * 16) * 64 + c1);
      #pragma unroll
      for (int n = 0; n < 4; ++n) bf[n] = *(const bf16x8*)(pB + (browb + n * 16) * 64 + c1);
      if (pre) { STAGE_A(t + 2, ss, 3); STAGE_B(t + 2, ss, 0); STAGE_B(t + 2, ss, 1); }
      __builtin_amdgcn_s_barrier();
      __builtin_amdgcn_s_setprio(1);
      #pragma unroll
      for (int m = 0; m < 4; ++m)
        #pragma unroll
        for (int n = 0; n < 4; ++n)
          acc[m][n] = MFMA16(af[m], bf[n], acc[m][n]);
      __builtin_amdgcn_s_setprio(0);
      // tile-end wait: next tile's 6 chunks are oldest outstanding
      if (t + 2 < NT)      asm volatile("s_waitcnt vmcnt(6)" ::: "memory");
      else if (t + 1 < NT) asm volatile("s_waitcnt vmcnt(0)" ::: "memory");
      __builtin_amdgcn_s_barrier();
    }

    sc = (sc == 2) ? 0 : sc + 1;
    ss = (ss == 2) ? 0 : ss + 1;
  }
#undef STAGE_A
#undef STAGE_B

  // epilogue: C/D layout col = lane&15, row = (lane>>4)*4 + reg
  const size_t row0 = (size_t)bm * BM + wm * 64;
  const int col0 = bn * BN + wn * 64;
  #pragma unroll
  for (int n = 0; n < 4; ++n) {
    const int col = col0 + n * 16 + fr;
    const float bv = bias[col];
    #pragma unroll
    for (int m = 0; m < 4; ++m) {
      const size_t r0 = row0 + m * 16 + fg * 4;
      #pragma unroll
      for (int r = 0; r < 4; ++r)
        C[(r0 + r) * N_DIM + col] = acc[m][n][r] + bv;
    }
  }
}

// ---------- launch ----------
extern "C" void kernel_launch(void* const* d_in, const int* in_sizes, int n_in,
                              void* d_out, int out_size, void* d_ws, size_t ws_size,
                              hipStream_t stream) {
  const float* x    = (const float*)d_in[0];
  const float* c0   = (const float*)d_in[1];
  const float* c1   = (const float*)d_in[2];
  const float* c2   = (const float*)d_in[3];
  const float* bias = (const float*)d_in[4];
  float* out = (float*)d_out;

  // workspace layout: Abf 16MB | Wt 32MB => 48MB needed
  const size_t NEED = (size_t)48 * 1024 * 1024;
  if (ws_size < NEED) return;

  char* ws = (char*)d_ws;
  ushort_t* Abf = (ushort_t*)ws;
  ushort_t* Wt  = (ushort_t*)(ws + (size_t)16 * 1024 * 1024);

  k_prep <<<6144, 256, 0, stream>>>(x, Abf, c0, c1, c2, Wt);
  k_gemm <<<256, 512, 0, stream>>>(Abf, Wt, bias, out);
}

// Round 5
// 106.581 us; speedup vs baseline: 2.1124x; 2.1124x over previous
//
#include <hip/hip_runtime.h>
#include <hip/hip_bf16.h>

typedef unsigned short ushort_t;
typedef __attribute__((ext_vector_type(4))) float f32x4;
typedef __attribute__((ext_vector_type(8))) short bf16x8;
typedef __attribute__((ext_vector_type(8))) unsigned short u16x8;

#define M_DIM 2048
#define N_DIM 4096
#define K_DIM 4096
#define BM 256
#define BN 128
#define BK 64
#define NT (K_DIM / BK)   // 64 K-tiles

#define MFMA16(a, b, c) __builtin_amdgcn_mfma_f32_16x16x32_bf16((a), (b), (c), 0, 0, 0)

// ---------- helpers ----------
__device__ __forceinline__ unsigned short f2bf(float f) {
  unsigned int u = __float_as_uint(f);
  u += 0x7FFFu + ((u >> 16) & 1u);   // round-to-nearest-even
  return (unsigned short)(u >> 16);
}

__device__ __forceinline__ void async16(void* l, const void* g) {
  __builtin_amdgcn_global_load_lds(
      (const __attribute__((address_space(1))) void*)g,
      (__attribute__((address_space(3))) void*)l,
      16, 0, 0);
}

// ---------- kernel 1: fused [x fp32->bf16] + [W build, c1 staged in LDS] ----------
// blocks [0,2048): convert x; blocks [2048,6144): one (o1,o2,o3) per block
__global__ void k_prep(const float* __restrict__ x, ushort_t* __restrict__ o,
                       const float* __restrict__ c0, const float* __restrict__ c1,
                       const float* __restrict__ c2, ushort_t* __restrict__ wt) {
  __shared__ float sc1[16 * 260];   // [i2][q*16+r], stride 260 (bank-spread)
  const int bid = blockIdx.x;
  const int tid = threadIdx.x;
  if (bid < 2048) {
    const int n4 = (M_DIM * K_DIM) / 4;
    for (int i = bid * 256 + tid; i < n4; i += 2048 * 256) {
      float4 v = ((const float4*)x)[i];
      ushort4 r;
      r.x = f2bf(v.x); r.y = f2bf(v.y); r.z = f2bf(v.z); r.w = f2bf(v.w);
      ((ushort4*)o)[i] = r;
    }
  } else {
    const int out = bid - 2048;               // 0..4095 = (o1,o2,o3)
    const int o3 = out & 15;
    const int o2 = (out >> 4) & 15;
    const int o1 = out >> 8;

    // --- stage c1 o2-slice into LDS: sc1[i2*260 + q*16 + r] = c1[q,i2,o2,r] ---
    {
      const int q  = tid >> 4;
      const int i2 = tid & 15;
      const float* src = c1 + q * 4096 + i2 * 256 + o2 * 16;
      float* dst = &sc1[i2 * 260 + q * 16];
      #pragma unroll
      for (int rr = 0; rr < 4; ++rr)
        *(float4*)(dst + rr * 4) = *(const float4*)(src + rr * 4);
    }
    __syncthreads();

    const int i2 = tid & 15;
    const int i1 = tid >> 4;

    // c0 row for (i1,o1): 16 floats, L1-resident vector loads
    float4 a4[4];
    {
      const float* c0p = c0 + (i1 * 16 + o1) * 16;
      #pragma unroll
      for (int rr = 0; rr < 4; ++rr) a4[rr] = *(const float4*)(c0p + rr * 4);
    }

    // t01r[r] = sum_q c0[i1,o1,q] * c1[q,i2,o2,r]   (c1 from LDS, broadcast reads)
    float t01r[16];
    #pragma unroll
    for (int r = 0; r < 16; ++r) t01r[r] = 0.f;
    #pragma unroll
    for (int q = 0; q < 16; ++q) {
      const float a = a4[q >> 2][q & 3];
      const float* sp = &sc1[i2 * 260 + q * 16];
      #pragma unroll
      for (int rr = 0; rr < 4; ++rr) {
        float4 v = *(const float4*)(sp + rr * 4);
        t01r[rr * 4 + 0] += a * v.x;
        t01r[rr * 4 + 1] += a * v.y;
        t01r[rr * 4 + 2] += a * v.z;
        t01r[rr * 4 + 3] += a * v.w;
      }
    }

    // out[i3] = sum_r t01r[r] * c2[r,i3,o3]  (c2 wave-uniform scalar loads)
    u16x8 lo, hi;
    #pragma unroll
    for (int i3 = 0; i3 < 16; ++i3) {
      const float* c2p = c2 + i3 * 16 + o3;
      float s = 0.f;
      #pragma unroll
      for (int rr = 0; rr < 16; ++rr) s += t01r[rr] * c2p[rr * 256];
      ushort_t v = f2bf(s);
      if (i3 < 8) lo[i3] = v; else hi[i3 - 8] = v;
    }
    u16x8* dst = (u16x8*)(wt + ((size_t)out << 12) + (i1 << 8) + (i2 << 4));
    dst[0] = lo;
    dst[1] = hi;
  }
}

// ---------- kernel 2: GEMM C[M][N] = A[M][K] * Wt[N][K]^T + bias ----------
// (unchanged from round 4: ~60us, 2 phases/K-tile, counted vmcnt, swizzle, setprio)
__global__ __launch_bounds__(512, 2) void k_gemm(
    const ushort_t* __restrict__ A,
    const ushort_t* __restrict__ Bt,
    const float* __restrict__ bias,
    float* __restrict__ C)
{
  __shared__ ushort_t lA[3][BM * BK];   // 3 x 32KB
  __shared__ ushort_t lB[3][BN * BK];   // 3 x 16KB  (total 144KB)

  const int tid  = threadIdx.x;
  const int lane = tid & 63;
  const int wid  = tid >> 6;     // 0..7
  const int wm   = wid >> 1;     // 0..3  (M quadrant, 64 rows)
  const int wn   = wid & 1;      // 0..1  (N half, 64 cols)
  const int fr   = lane & 15;
  const int fg   = lane >> 4;    // 0..3

  const int bid = blockIdx.x;
  const int bm  = bid & 7;       // 0..7
  const int bn  = bid >> 3;      // 0..31

  const int srow = tid >> 3;                               // 0..63
  const int scol = ((tid & 7) ^ (srow & 7)) << 3;          // swizzled source col (elems)
  const ushort_t* aSt = A  + (size_t)(bm * BM + srow) * K_DIM + scol;
  const ushort_t* bSt = Bt + (size_t)(bn * BN + srow) * K_DIM + scol;
  const int dE = tid * 8;                                  // linear dest (elems)

#define STAGE_A(kt, s, r_) async16(&lA[s][(r_) * 4096 + dE], \
                                   aSt + (size_t)(kt) * BK + (size_t)(r_) * 64 * K_DIM)
#define STAGE_B(kt, s, r_) async16(&lB[s][(r_) * 4096 + dE], \
                                   bSt + (size_t)(kt) * BK + (size_t)(r_) * 64 * K_DIM)

  const int arowb = wm * 64 + fr;                // + m*16
  const int browb = wn * 64 + fr;                // + n*16
  const int c0 = ( fg      ^ (fr & 7)) << 3;     // kk=0 col (elems)
  const int c1 = ((fg + 4) ^ (fr & 7)) << 3;     // kk=1

  f32x4 acc[4][4];
  #pragma unroll
  for (int m = 0; m < 4; ++m)
    #pragma unroll
    for (int n = 0; n < 4; ++n)
      acc[m][n] = (f32x4){0.f, 0.f, 0.f, 0.f};

  #pragma unroll
  for (int r_ = 0; r_ < 4; ++r_) STAGE_A(0, 0, r_);
  #pragma unroll
  for (int r_ = 0; r_ < 2; ++r_) STAGE_B(0, 0, r_);
  #pragma unroll
  for (int r_ = 0; r_ < 4; ++r_) STAGE_A(1, 1, r_);
  #pragma unroll
  for (int r_ = 0; r_ < 2; ++r_) STAGE_B(1, 1, r_);

  asm volatile("s_waitcnt vmcnt(6)" ::: "memory");   // tile 0 resident (per-wave)
  __builtin_amdgcn_s_barrier();                      // ... for ALL waves

  int sc = 0, ss = 2;
  for (int t = 0; t < NT; ++t) {
    const bool pre = (t + 2 < NT);
    const ushort_t* pA = &lA[sc][0];
    const ushort_t* pB = &lB[sc][0];

    // ================= phase 0: kk=0 (16 MFMA) =================
    {
      bf16x8 af[4], bf[4];
      #pragma unroll
      for (int m = 0; m < 4; ++m) af[m] = *(const bf16x8*)(pA + (arowb + m * 16) * 64 + c0);
      #pragma unroll
      for (int n = 0; n < 4; ++n) bf[n] = *(const bf16x8*)(pB + (browb + n * 16) * 64 + c0);
      if (pre) { STAGE_A(t + 2, ss, 0); STAGE_A(t + 2, ss, 1); STAGE_A(t + 2, ss, 2); }
      __builtin_amdgcn_s_barrier();
      __builtin_amdgcn_s_setprio(1);
      #pragma unroll
      for (int m = 0; m < 4; ++m)
        #pragma unroll
        for (int n = 0; n < 4; ++n)
          acc[m][n] = MFMA16(af[m], bf[n], acc[m][n]);
      __builtin_amdgcn_s_setprio(0);
      __builtin_amdgcn_s_barrier();
    }

    // ================= phase 1: kk=1 (16 MFMA) =================
    {
      bf16x8 af[4], bf[4];
      #pragma unroll
      for (int m = 0; m < 4; ++m) af[m] = *(const bf16x8*)(pA + (arowb + m * 16) * 64 + c1);
      #pragma unroll
      for (int n = 0; n < 4; ++n) bf[n] = *(const bf16x8*)(pB + (browb + n * 16) * 64 + c1);
      if (pre) { STAGE_A(t + 2, ss, 3); STAGE_B(t + 2, ss, 0); STAGE_B(t + 2, ss, 1); }
      __builtin_amdgcn_s_barrier();
      __builtin_amdgcn_s_setprio(1);
      #pragma unroll
      for (int m = 0; m < 4; ++m)
        #pragma unroll
        for (int n = 0; n < 4; ++n)
          acc[m][n] = MFMA16(af[m], bf[n], acc[m][n]);
      __builtin_amdgcn_s_setprio(0);
      if (t + 2 < NT)      asm volatile("s_waitcnt vmcnt(6)" ::: "memory");
      else if (t + 1 < NT) asm volatile("s_waitcnt vmcnt(0)" ::: "memory");
      __builtin_amdgcn_s_barrier();
    }

    sc = (sc == 2) ? 0 : sc + 1;
    ss = (ss == 2) ? 0 : ss + 1;
  }
#undef STAGE_A
#undef STAGE_B

  // epilogue: C/D layout col = lane&15, row = (lane>>4)*4 + reg
  const size_t row0 = (size_t)bm * BM + wm * 64;
  const int col0 = bn * BN + wn * 64;
  #pragma unroll
  for (int n = 0; n < 4; ++n) {
    const int col = col0 + n * 16 + fr;
    const float bv = bias[col];
    #pragma unroll
    for (int m = 0; m < 4; ++m) {
      const size_t r0 = row0 + m * 16 + fg * 4;
      #pragma unroll
      for (int r = 0; r < 4; ++r)
        C[(r0 + r) * N_DIM + col] = acc[m][n][r] + bv;
    }
  }
}

// ---------- launch ----------
extern "C" void kernel_launch(void* const* d_in, const int* in_sizes, int n_in,
                              void* d_out, int out_size, void* d_ws, size_t ws_size,
                              hipStream_t stream) {
  const float* x    = (const float*)d_in[0];
  const float* c0   = (const float*)d_in[1];
  const float* c1   = (const float*)d_in[2];
  const float* c2   = (const float*)d_in[3];
  const float* bias = (const float*)d_in[4];
  float* out = (float*)d_out;

  // workspace layout: Abf 16MB | Wt 32MB => 48MB needed
  const size_t NEED = (size_t)48 * 1024 * 1024;
  if (ws_size < NEED) return;

  char* ws = (char*)d_ws;
  ushort_t* Abf = (ushort_t*)ws;
  ushort_t* Wt  = (ushort_t*)(ws + (size_t)16 * 1024 * 1024);

  k_prep <<<6144, 256, 0, stream>>>(x, Abf, c0, c1, c2, Wt);
  k_gemm <<<256, 512, 0, stream>>>(Abf, Wt, bias, out);
}